// Round 6
// baseline (724.149 us; speedup 1.0000x reference)
//
#include <hip/hip_runtime.h>
#include <hip/hip_bf16.h>
#include <math.h>

#define NN 4096
#define CD 768
#define HD 512
#define OD 50
#define FGD 818   // CD + OD

typedef double v4d __attribute__((ext_vector_type(4)));
typedef short short8 __attribute__((ext_vector_type(8)));
typedef float f32x4 __attribute__((ext_vector_type(4)));
typedef unsigned short us4 __attribute__((ext_vector_type(4)));
typedef unsigned short ushortT;

__device__ inline ushortT f2bf(float v) {
    __hip_bfloat16 b = __float2bfloat16(v);
    return *(ushortT*)&b;
}

// ---------------------------------------------------------------------------
// K1: sim = x @ x^T via fp64 MFMA, runtime-probed C/D layout (verified R3+R5).
// v2: LDS cut to 18.5 KB (fp32 staging; mirror transpose in two 32-col passes
// reusing the staging buffer) for higher occupancy; cross-label threshold
// sum FUSED into the epilogue (from registers, fp64 atomics).
// ---------------------------------------------------------------------------
__global__ __launch_bounds__(256) void sim_mfma(const float* __restrict__ x,
                                                const int* __restrict__ labels,
                                                double* __restrict__ sim,
                                                double* __restrict__ scal) {
    int bx = blockIdx.x, by = blockIdx.y;
    if (bx < by) return;                    // upper triangle only
    __shared__ double smem[2304];           // 18432 B, aliased
    __shared__ double reds[8];
    float* XrF = (float*)smem;              // [64][36] fp32
    float* XcF = XrF + 64 * 36;
    int tid = threadIdx.x;
    int lane = tid & 63;
    int w = tid >> 6;
    int wr = w >> 1, wc = w & 1;
    int row0 = by * 64, col0 = bx * 64;
    int m = lane & 15, kf = lane >> 4;

    // runtime C/D layout probe
    v4d zed = {0.0, 0.0, 0.0, 0.0};
    double idv = (double)m;
    double sel = (kf == 0) ? 1.0 : 0.0;
    v4d pr = __builtin_amdgcn_mfma_f64_16x16x4f64(idv, sel, zed, 0, 0, 0);
    v4d pc = __builtin_amdgcn_mfma_f64_16x16x4f64(sel, idv, zed, 0, 0, 0);
    int prow[4], pcol[4];
#pragma unroll
    for (int r = 0; r < 4; ++r) { prow[r] = (int)pr[r]; pcol[r] = (int)pc[r]; }

    v4d acc[2][2] = {{{0.0, 0.0, 0.0, 0.0}, {0.0, 0.0, 0.0, 0.0}},
                     {{0.0, 0.0, 0.0, 0.0}, {0.0, 0.0, 0.0, 0.0}}};

    for (int k0 = 0; k0 < CD; k0 += 32) {
#pragma unroll
        for (int t = 0; t < 2; ++t) {
            int id2 = tid + t * 256;
            int row = id2 >> 3, f4 = id2 & 7;
            *(float4*)&XrF[row * 36 + f4 * 4] =
                *(const float4*)&x[(size_t)(row0 + row) * CD + k0 + f4 * 4];
            *(float4*)&XcF[row * 36 + f4 * 4] =
                *(const float4*)&x[(size_t)(col0 + row) * CD + k0 + f4 * 4];
        }
        __syncthreads();
#pragma unroll
        for (int kk = 0; kk < 8; ++kk) {
            double A0 = (double)XrF[(wr * 32 + m) * 36 + kk * 4 + kf];
            double A1 = (double)XrF[(wr * 32 + 16 + m) * 36 + kk * 4 + kf];
            double B0 = (double)XcF[(wc * 32 + m) * 36 + kk * 4 + kf];
            double B1 = (double)XcF[(wc * 32 + 16 + m) * 36 + kk * 4 + kf];
            acc[0][0] = __builtin_amdgcn_mfma_f64_16x16x4f64(A0, B0, acc[0][0], 0, 0, 0);
            acc[0][1] = __builtin_amdgcn_mfma_f64_16x16x4f64(A0, B1, acc[0][1], 0, 0, 0);
            acc[1][0] = __builtin_amdgcn_mfma_f64_16x16x4f64(A1, B0, acc[1][0], 0, 0, 0);
            acc[1][1] = __builtin_amdgcn_mfma_f64_16x16x4f64(A1, B1, acc[1][1], 0, 0, 0);
        }
        __syncthreads();
    }

    // ---- fused cross-label threshold partial sum (from registers) ----
    {
        int lr[2][4], lc[2][4];
#pragma unroll
        for (int i = 0; i < 2; ++i)
#pragma unroll
            for (int r = 0; r < 4; ++r)
                lr[i][r] = labels[row0 + wr * 32 + i * 16 + prow[r]];
#pragma unroll
        for (int j = 0; j < 2; ++j)
#pragma unroll
            for (int r = 0; r < 4; ++r)
                lc[j][r] = labels[col0 + wc * 32 + j * 16 + pcol[r]];
        double ssum = 0.0, scnt = 0.0;
#pragma unroll
        for (int i = 0; i < 2; ++i)
#pragma unroll
            for (int j = 0; j < 2; ++j)
#pragma unroll
                for (int r = 0; r < 4; ++r)
                    if (lr[i][r] != lc[j][r]) { ssum += acc[i][j][r]; scnt += 1.0; }
        if (bx > by) { ssum *= 2.0; scnt *= 2.0; }   // mirror contributes equally
        for (int off = 32; off; off >>= 1) {
            ssum += __shfl_down(ssum, off);
            scnt += __shfl_down(scnt, off);
        }
        if (lane == 0) { reds[w] = ssum; reds[4 + w] = scnt; }
        __syncthreads();
        if (tid == 0) {
            atomicAdd(&scal[0], reds[0] + reds[1] + reds[2] + reds[3]);
            atomicAdd(&scal[1], reds[4] + reds[5] + reds[6] + reds[7]);
        }
    }

    // direct (row-major) write
#pragma unroll
    for (int i = 0; i < 2; ++i)
#pragma unroll
        for (int j = 0; j < 2; ++j) {
            int rbase = wr * 32 + i * 16, cbase = wc * 32 + j * 16;
#pragma unroll
            for (int r = 0; r < 4; ++r) {
                sim[(size_t)(row0 + rbase + prow[r]) * NN + col0 + cbase + pcol[r]] =
                    acc[i][j][r];
            }
        }

    // mirror write via two 32-column LDS transpose passes (skip diagonal)
    if (bx > by) {
        double* T32 = smem;                 // [32][65] doubles = 16640 B
        __syncthreads();
#pragma unroll
        for (int h = 0; h < 2; ++h) {
            if (wc == h) {
#pragma unroll
                for (int i = 0; i < 2; ++i)
#pragma unroll
                    for (int j = 0; j < 2; ++j)
#pragma unroll
                        for (int r = 0; r < 4; ++r)
                            T32[(j * 16 + pcol[r]) * 65 + wr * 32 + i * 16 + prow[r]] =
                                acc[i][j][r];
            }
            __syncthreads();
            for (int t = tid; t < 2048; t += 256) {
                int cc = t >> 6, rr = t & 63;
                sim[(size_t)(col0 + h * 32 + cc) * NN + row0 + rr] = T32[cc * 65 + rr];
            }
            __syncthreads();
        }
    }
}

// ---------------------------------------------------------------------------
// K3: mask pass (4-wide vectorized) -> loss_mask fp32 (d_out), adjacency bf16
// (exact 0/1), degrees. One block per row.
// ---------------------------------------------------------------------------
__global__ __launch_bounds__(256) void mask_kernel(const double* __restrict__ sim,
                                                   const int* __restrict__ labels,
                                                   const double* __restrict__ scal,
                                                   ushortT* __restrict__ ab,
                                                   float* __restrict__ lm,
                                                   int* __restrict__ deg) {
    int i = blockIdx.x;
    int li = labels[i];
    double cnt = scal[1];
    double thr = (cnt > 0.0) ? (scal[0] / cnt) : 0.0;
    int count = 0;
    const double* srow = sim + (size_t)i * NN;
    for (int j4 = threadIdx.x * 4; j4 < NN; j4 += 1024) {
        double2 s01 = *(const double2*)&srow[j4];
        double2 s23 = *(const double2*)&srow[j4 + 2];
        int4 lab = *(const int4*)&labels[j4];
        double sv[4] = {s01.x, s01.y, s23.x, s23.y};
        int lb[4] = {lab.x, lab.y, lab.z, lab.w};
        float4 lmv;
        us4 abv;
        float* lmp = (float*)&lmv;
#pragma unroll
        for (int jj = 0; jj < 4; ++jj) {
            int j = j4 + jj;
            bool edge = (j != i) && (lb[jj] == li) && (sv[jj] <= thr);
            count += edge ? 1 : 0;
            abv[jj] = (j == i || edge) ? (ushortT)0x3F80 : (ushortT)0;
            lmp[jj] = (edge && (i < j)) ? 1.0f : 0.0f;
        }
        *(float4*)&lm[(size_t)i * NN + j4] = lmv;
        *(us4*)&ab[(size_t)i * NN + j4] = abv;
    }
    for (int off = 32; off; off >>= 1) count += __shfl_down(count, off);
    __shared__ int cw[4];
    int wid = threadIdx.x >> 6, lane = threadIdx.x & 63;
    if (lane == 0) cw[wid] = count;
    __syncthreads();
    if (threadIdx.x == 0) deg[i] = 1 + cw[0] + cw[1] + cw[2] + cw[3];
}

__global__ void dinv_kernel(const int* __restrict__ deg, float* __restrict__ dinv) {
    int i = blockIdx.x * blockDim.x + threadIdx.x;
    if (i < NN) dinv[i] = (float)(1.0 / sqrt((double)deg[i]));
}

// ---------------------------------------------------------------------------
// fp32 row-major -> bf16 row-major
// ---------------------------------------------------------------------------
__global__ __launch_bounds__(256) void to_bf16(const float* __restrict__ X,
                                               ushortT* __restrict__ Xb, size_t total) {
    for (size_t i = (size_t)blockIdx.x * blockDim.x + threadIdx.x; i < total;
         i += (size_t)gridDim.x * blockDim.x)
        Xb[i] = f2bf(X[i]);
}

// ---------------------------------------------------------------------------
// transpose: P[K][N] fp32 -> T[Npad][K] bf16 (rows n>=N zeroed)
// ---------------------------------------------------------------------------
__global__ __launch_bounds__(256) void transp_bf16(const float* __restrict__ P,
                                                   ushortT* __restrict__ T,
                                                   int K, int N, int Npad) {
    __shared__ float t[32][33];
    int k0 = blockIdx.x * 32, n0 = blockIdx.y * 32;
    int tx = threadIdx.x & 31, ty = threadIdx.x >> 5;   // ty: 0..7
#pragma unroll
    for (int s = 0; s < 4; ++s) {
        int k = k0 + ty + s * 8, n = n0 + tx;
        t[ty + s * 8][tx] = (k < K && n < N) ? P[(size_t)k * N + n] : 0.0f;
    }
    __syncthreads();
#pragma unroll
    for (int s = 0; s < 4; ++s) {
        int n = n0 + ty + s * 8, k = k0 + tx;
        if (n < Npad && k < K) T[(size_t)n * K + k] = f2bf(t[tx][ty + s * 8]);
    }
}

// ---------------------------------------------------------------------------
// bf16-MFMA GEMM, single-plane operands.
// A: row-major M x K bf16. B: TRANSPOSED [Npad][K] bf16.
// C = epi( rowscale[r] * (A@B) [+ bias] [relu] )
// EPI: 0 = fp32 to C (ldc), 1 = bf16 row-major to Cb (ldc),
//      2 = bf16 transposed to Cb ([Npad][M], via LDS transpose)
// Block 256 = 4 waves; 64x64 tile; wave -> 32x32 (2x2 frags of 16x16x32).
// ---------------------------------------------------------------------------
template <bool RELU, bool HASBIAS, int EPI>
__global__ __launch_bounds__(256) void gemm_bf16(
    const ushortT* __restrict__ A, const ushortT* __restrict__ B,
    float* __restrict__ C, ushortT* __restrict__ Cb,
    int M, int Nn, int K, int ldc,
    const float* __restrict__ rowscale, const float* __restrict__ bias) {
    __shared__ ushortT lds[2 * 64 * 72];    // 18432 B
    int tid = threadIdx.x;
    int lane = tid & 63;
    int w = tid >> 6;
    int wr = w >> 1, wc = w & 1;
    int m = lane & 15, quad = lane >> 4;
    int row0 = blockIdx.y * 64, col0 = blockIdx.x * 64;

    f32x4 acc[2][2] = {{{0.f, 0.f, 0.f, 0.f}, {0.f, 0.f, 0.f, 0.f}},
                       {{0.f, 0.f, 0.f, 0.f}, {0.f, 0.f, 0.f, 0.f}}};

    for (int k0 = 0; k0 < K; k0 += 64) {
#pragma unroll
        for (int t = 0; t < 2; ++t) {
            int id2 = tid + t * 256;
            int row = id2 >> 3, c8 = (id2 & 7) * 8;
            *(short8*)&lds[row * 72 + c8] =
                *(const short8*)&A[(size_t)(row0 + row) * K + k0 + c8];
            *(short8*)&lds[4608 + row * 72 + c8] =
                *(const short8*)&B[(size_t)(col0 + row) * K + k0 + c8];
        }
        __syncthreads();
#pragma unroll
        for (int ks = 0; ks < 2; ++ks) {
            short8 af[2], bf[2];
#pragma unroll
            for (int i = 0; i < 2; ++i)
                af[i] = *(const short8*)&lds[(wr * 32 + i * 16 + m) * 72 +
                                             ks * 32 + quad * 8];
#pragma unroll
            for (int j = 0; j < 2; ++j)
                bf[j] = *(const short8*)&lds[4608 + (wc * 32 + j * 16 + m) * 72 +
                                             ks * 32 + quad * 8];
#pragma unroll
            for (int i = 0; i < 2; ++i)
#pragma unroll
                for (int j = 0; j < 2; ++j)
                    acc[i][j] = __builtin_amdgcn_mfma_f32_16x16x32_bf16(
                        af[i], bf[j], acc[i][j], 0, 0, 0);
        }
        __syncthreads();
    }

    if (EPI == 2) {
        ushortT* Th = lds;                  // 64 x 72
#pragma unroll
        for (int i = 0; i < 2; ++i)
#pragma unroll
            for (int j = 0; j < 2; ++j)
#pragma unroll
                for (int r = 0; r < 4; ++r) {
                    int row = wr * 32 + i * 16 + quad * 4 + r;
                    int col = wc * 32 + j * 16 + m;
                    Th[col * 72 + row] = f2bf(acc[i][j][r] * rowscale[row0 + row]);
                }
        __syncthreads();
#pragma unroll
        for (int t = 0; t < 2; ++t) {
            int id2 = tid + t * 256;
            int cc = id2 >> 3, chunk = id2 & 7;
            *(short8*)&Cb[(size_t)(col0 + cc) * M + row0 + chunk * 8] =
                *(const short8*)&Th[cc * 72 + chunk * 8];
        }
    } else {
#pragma unroll
        for (int i = 0; i < 2; ++i)
#pragma unroll
            for (int j = 0; j < 2; ++j)
#pragma unroll
                for (int r = 0; r < 4; ++r) {
                    int row = wr * 32 + i * 16 + quad * 4 + r;
                    int col = wc * 32 + j * 16 + m;
                    int gr = row0 + row, gc = col0 + col;
                    if (gc < Nn) {
                        float v = acc[i][j][r] * rowscale[gr];
                        if (HASBIAS) v += bias[gc];
                        if (RELU) v = fmaxf(v, 0.0f);
                        if (EPI == 0) C[(size_t)gr * ldc + gc] = v;
                        else Cb[(size_t)gr * ldc + gc] = f2bf(v);
                    }
                }
    }
}

// ---------------------------------------------------------------------------
// Copy x into f_g[:, 0:768] and into the x output region.
// ---------------------------------------------------------------------------
__global__ __launch_bounds__(256) void copy_x(const float* __restrict__ x,
                                              float* __restrict__ fg,
                                              float* __restrict__ xo) {
    size_t total = (size_t)NN * CD;
    for (size_t idx = (size_t)blockIdx.x * blockDim.x + threadIdx.x; idx < total;
         idx += (size_t)gridDim.x * blockDim.x) {
        size_t i = idx / CD, c = idx - i * CD;
        float v = x[idx];
        fg[i * FGD + c] = v;
        xo[idx] = v;
    }
}

// ---------------------------------------------------------------------------
// out[i] = f_g[i,:] . fcW + fcb
// ---------------------------------------------------------------------------
__global__ __launch_bounds__(256) void out_kernel(const float* __restrict__ fg,
                                                  const float* __restrict__ fcW,
                                                  const float* __restrict__ fcb,
                                                  float* __restrict__ out) {
    int i = blockIdx.x;
    float s = 0.0f;
    for (int j = threadIdx.x; j < FGD; j += 256)
        s += fg[(size_t)i * FGD + j] * fcW[j];
    for (int off = 32; off; off >>= 1) s += __shfl_down(s, off);
    __shared__ float sw[4];
    int wid = threadIdx.x >> 6, lane = threadIdx.x & 63;
    if (lane == 0) sw[wid] = s;
    __syncthreads();
    if (threadIdx.x == 0) out[i] = sw[0] + sw[1] + sw[2] + sw[3] + fcb[0];
}

extern "C" void kernel_launch(void* const* d_in, const int* in_sizes, int n_in,
                              void* d_out, int out_size, void* d_ws, size_t ws_size,
                              hipStream_t stream) {
    const float* x = (const float*)d_in[0];
    const int* labels = (const int*)d_in[1];
    const float* W1 = (const float*)d_in[2];
    const float* b1 = (const float*)d_in[3];
    const float* W2 = (const float*)d_in[4];
    const float* b2 = (const float*)d_in[5];
    const float* fcW = (const float*)d_in[6];
    const float* fcb = (const float*)d_in[7];
    float* outp = (float*)d_out;

    const size_t o_out = 0;
    const size_t o_fg = 4096;
    const size_t o_lm = o_fg + (size_t)NN * FGD;
    const size_t o_x = o_lm + (size_t)NN * NN;

    // workspace layout
    char* ws = (char*)d_ws;
    size_t off = 0;
    double* sim = (double*)(ws + off); off += (size_t)NN * NN * 8;      // 128 MiB
    ushortT* ab = (ushortT*)(ws + off); off += (size_t)NN * NN * 2;     // 32 MiB
    ushortT* xb = (ushortT*)(ws + off); off += (size_t)NN * CD * 2;
    ushortT* w1t = (ushortT*)(ws + off); off += (size_t)HD * CD * 2;
    ushortT* xw1sT = (ushortT*)(ws + off); off += (size_t)HD * NN * 2;
    ushortT* hb = (ushortT*)(ws + off); off += (size_t)NN * HD * 2;
    ushortT* w2t = (ushortT*)(ws + off); off += (size_t)64 * HD * 2;
    ushortT* hw2sT = (ushortT*)(ws + off); off += (size_t)64 * NN * 2;
    int* deg = (int*)(ws + off); off += (size_t)NN * 4;
    float* dinv = (float*)(ws + off); off += (size_t)NN * 4;
    double* scal = (double*)(ws + off); off += 16;

    hipMemsetAsync(scal, 0, 2 * sizeof(double), stream);

    // K1: sim = x @ x^T (fp64 MFMA) + fused cross-label threshold sums
    sim_mfma<<<dim3(64, 64), 256, 0, stream>>>(x, labels, sim, scal);

    // K3: mask + bf16 adjacency + degrees
    mask_kernel<<<NN, 256, 0, stream>>>(sim, labels, scal, ab, outp + o_lm, deg);
    dinv_kernel<<<(NN + 255) / 256, 256, 0, stream>>>(deg, dinv);

    // operand prep
    to_bf16<<<4096, 256, 0, stream>>>(x, xb, (size_t)NN * CD);
    transp_bf16<<<dim3(CD / 32, HD / 32), 256, 0, stream>>>(W1, w1t, CD, HD, HD);
    transp_bf16<<<dim3(HD / 32, 2), 256, 0, stream>>>(W2, w2t, HD, OD, 64);

    // K4: xw1sT = (dinv ⊙ (x @ W1))^T   [M=4096,N=512,K=768]
    gemm_bf16<false, false, 2><<<dim3(HD / 64, NN / 64), 256, 0, stream>>>(
        xb, w1t, nullptr, xw1sT, NN, HD, CD, 0, dinv, nullptr);

    // K5: h = relu(dinv ⊙ (a @ xw1s) + b1), bf16 row-major  [K=4096]
    gemm_bf16<true, true, 1><<<dim3(HD / 64, NN / 64), 256, 0, stream>>>(
        ab, xw1sT, nullptr, hb, NN, HD, NN, HD, dinv, b1);

    // K6: hw2sT = (dinv ⊙ (h @ W2))^T   [N=50->64, K=512]
    gemm_bf16<false, false, 2><<<dim3(1, NN / 64), 256, 0, stream>>>(
        hb, w2t, nullptr, hw2sT, NN, OD, HD, 0, dinv, nullptr);

    // K7: g = dinv ⊙ (a @ hw2s) + b2 -> f_g[:, 768:818] fp32  [K=4096]
    gemm_bf16<false, true, 0><<<dim3(1, NN / 64), 256, 0, stream>>>(
        ab, hw2sT, outp + o_fg + CD, nullptr, NN, OD, NN, FGD, dinv, b2);

    copy_x<<<8192, 256, 0, stream>>>(x, outp + o_fg, outp + o_x);

    out_kernel<<<NN, 256, 0, stream>>>(outp + o_fg, fcW, fcb, outp + o_out);
}

// Round 7
// 649.280 us; speedup vs baseline: 1.1153x; 1.1153x over previous
//
#include <hip/hip_runtime.h>
#include <hip/hip_bf16.h>
#include <math.h>

#define NN 4096
#define CD 768
#define HD 512
#define OD 50
#define FGD 818   // CD + OD

typedef double v4d __attribute__((ext_vector_type(4)));
typedef short short8 __attribute__((ext_vector_type(8)));
typedef float f32x4 __attribute__((ext_vector_type(4)));
typedef unsigned short us4 __attribute__((ext_vector_type(4)));
typedef unsigned short ushortT;
typedef unsigned char uchar;

__device__ inline ushortT f2bf(float v) {
    __hip_bfloat16 b = __float2bfloat16(v);
    return *(ushortT*)&b;
}

// ---------------------------------------------------------------------------
// K0a: per-label group sums of x columns (fp64).  gsum[0..767]=L0, [768..]=L1
// ---------------------------------------------------------------------------
__global__ __launch_bounds__(256) void gsum_kernel(const float* __restrict__ x,
                                                   const int* __restrict__ labels,
                                                   double* __restrict__ gsum) {
    int b = blockIdx.x;                     // 256 blocks x 16 rows
    int t = threadIdx.x;
    double a0[3] = {0, 0, 0}, a1[3] = {0, 0, 0};
    for (int rr = 0; rr < 16; ++rr) {
        int row = b * 16 + rr;
        int lab = labels[row];
#pragma unroll
        for (int s = 0; s < 3; ++s) {
            double v = (double)x[(size_t)row * CD + t + s * 256];
            if (lab == 0) a0[s] += v; else a1[s] += v;
        }
    }
#pragma unroll
    for (int s = 0; s < 3; ++s) {
        atomicAdd(&gsum[t + s * 256], a0[s]);
        atomicAdd(&gsum[768 + t + s * 256], a1[s]);
    }
}

// ---------------------------------------------------------------------------
// K0b: threshold scalars. scal[0] = 2*S0.S1 (cross-label sim sum),
//      scal[1] = 2*n0*n1 (cross-label ordered pair count).
// ---------------------------------------------------------------------------
__global__ __launch_bounds__(256) void gdot_kernel(const double* __restrict__ gsum,
                                                   const int* __restrict__ labels,
                                                   double* __restrict__ scal) {
    int t = threadIdx.x;
    double d = 0.0;
    for (int c = t; c < CD; c += 256) d += gsum[c] * gsum[768 + c];
    int n0 = 0;
    for (int i = t; i < NN; i += 256) n0 += (labels[i] == 0) ? 1 : 0;
    for (int off = 32; off; off >>= 1) {
        d += __shfl_down(d, off);
        n0 += __shfl_down(n0, off);
    }
    __shared__ double sd[4];
    __shared__ int sn[4];
    int wid = t >> 6, lane = t & 63;
    if (lane == 0) { sd[wid] = d; sn[wid] = n0; }
    __syncthreads();
    if (t == 0) {
        double D = sd[0] + sd[1] + sd[2] + sd[3];
        double N0 = (double)(sn[0] + sn[1] + sn[2] + sn[3]);
        scal[0] = 2.0 * D;
        scal[1] = 2.0 * N0 * ((double)NN - N0);
    }
}

// ---------------------------------------------------------------------------
// K1: FUSED sim+mask. fp64 MFMA x@x^T tile (runtime-probed C/D layout,
// verified R3/R5/R6) -> edge flags in LDS -> ab (bf16 0/1), lm (fp32 0/1),
// deg atomics. sim matrix never materialized. Triangular 2080-block grid.
// ---------------------------------------------------------------------------
__global__ __launch_bounds__(256) void sim_fused(const float* __restrict__ x,
                                                 const int* __restrict__ labels,
                                                 const double* __restrict__ scal,
                                                 ushortT* __restrict__ ab,
                                                 float* __restrict__ lm,
                                                 int* __restrict__ deg) {
    // triangular mapping: t -> (by, bx), bx >= by, row by holds 64-by blocks
    int t = blockIdx.x;
    int by = (int)((129.0 - sqrt(16641.0 - 8.0 * (double)t)) * 0.5);
    while (by * (129 - by) / 2 > t) --by;
    while ((by + 1) * (129 - (by + 1)) / 2 <= t) ++by;
    int bx = by + (t - by * (129 - by) / 2);
    bool diag = (bx == by);

    __shared__ double smem[2304];           // 18432 B: staging, then flags
    __shared__ int larr[128];
    float* XrF = (float*)smem;              // [64][36] fp32
    float* XcF = XrF + 64 * 36;
    int tid = threadIdx.x;
    int lane = tid & 63;
    int w = tid >> 6;
    int wr = w >> 1, wc = w & 1;
    int row0 = by * 64, col0 = bx * 64;
    int m = lane & 15, kf = lane >> 4;

    if (tid < 64) larr[tid] = labels[row0 + tid];
    else if (tid < 128) larr[tid] = labels[col0 + tid - 64];

    // runtime C/D layout probe
    v4d zed = {0.0, 0.0, 0.0, 0.0};
    double idv = (double)m;
    double sel = (kf == 0) ? 1.0 : 0.0;
    v4d pr = __builtin_amdgcn_mfma_f64_16x16x4f64(idv, sel, zed, 0, 0, 0);
    v4d pc = __builtin_amdgcn_mfma_f64_16x16x4f64(sel, idv, zed, 0, 0, 0);
    int prow[4], pcol[4];
#pragma unroll
    for (int r = 0; r < 4; ++r) { prow[r] = (int)pr[r]; pcol[r] = (int)pc[r]; }

    v4d acc[2][2] = {{{0.0, 0.0, 0.0, 0.0}, {0.0, 0.0, 0.0, 0.0}},
                     {{0.0, 0.0, 0.0, 0.0}, {0.0, 0.0, 0.0, 0.0}}};

    for (int k0 = 0; k0 < CD; k0 += 32) {
#pragma unroll
        for (int tt = 0; tt < 2; ++tt) {
            int id2 = tid + tt * 256;
            int row = id2 >> 3, f4 = id2 & 7;
            *(float4*)&XrF[row * 36 + f4 * 4] =
                *(const float4*)&x[(size_t)(row0 + row) * CD + k0 + f4 * 4];
            *(float4*)&XcF[row * 36 + f4 * 4] =
                *(const float4*)&x[(size_t)(col0 + row) * CD + k0 + f4 * 4];
        }
        __syncthreads();
#pragma unroll
        for (int kk = 0; kk < 8; ++kk) {
            double A0 = (double)XrF[(wr * 32 + m) * 36 + kk * 4 + kf];
            double A1 = (double)XrF[(wr * 32 + 16 + m) * 36 + kk * 4 + kf];
            double B0 = (double)XcF[(wc * 32 + m) * 36 + kk * 4 + kf];
            double B1 = (double)XcF[(wc * 32 + 16 + m) * 36 + kk * 4 + kf];
            acc[0][0] = __builtin_amdgcn_mfma_f64_16x16x4f64(A0, B0, acc[0][0], 0, 0, 0);
            acc[0][1] = __builtin_amdgcn_mfma_f64_16x16x4f64(A0, B1, acc[0][1], 0, 0, 0);
            acc[1][0] = __builtin_amdgcn_mfma_f64_16x16x4f64(A1, B0, acc[1][0], 0, 0, 0);
            acc[1][1] = __builtin_amdgcn_mfma_f64_16x16x4f64(A1, B1, acc[1][1], 0, 0, 0);
        }
        __syncthreads();   // also protects the flag-alias below
    }

    // ---- edge flags into LDS (alias the staging buffer) ----
    double cnt = scal[1];
    double thr = (cnt > 0.0) ? (scal[0] / cnt) : 0.0;
    uchar* flags = (uchar*)smem;            // [64][68]
#pragma unroll
    for (int i = 0; i < 2; ++i)
#pragma unroll
        for (int j = 0; j < 2; ++j) {
            int rbase = wr * 32 + i * 16, cbase = wc * 32 + j * 16;
#pragma unroll
            for (int r = 0; r < 4; ++r) {
                int row = rbase + prow[r], col = cbase + pcol[r];
                bool edge = ((row0 + row) != (col0 + col)) &&
                            (larr[row] == larr[64 + col]) && (acc[i][j][r] <= thr);
                flags[row * 68 + col] = edge ? 1 : 0;
            }
        }
    __syncthreads();

    // ---- write ab/lm rows for (by,bx) region + row degrees ----
    {
        int r = tid >> 2, q = tid & 3;      // 4 threads per row, 16 cols each
        int cnti = 0;
#pragma unroll
        for (int s = 0; s < 4; ++s) {
            int cb = q * 16 + s * 4;
            float4 f;
            us4 a4;
#pragma unroll
            for (int k2 = 0; k2 < 4; ++k2) {
                int c = cb + k2;
                bool fl = flags[r * 68 + c] != 0;
                cnti += fl ? 1 : 0;
                ((ushortT*)&a4)[k2] =
                    (fl || (diag && r == c)) ? (ushortT)0x3F80 : (ushortT)0;
                ((float*)&f)[k2] = (fl && (row0 + r < col0 + c)) ? 1.0f : 0.0f;
            }
            *(us4*)&ab[(size_t)(row0 + r) * NN + col0 + cb] = a4;
            *(float4*)&lm[(size_t)(row0 + r) * NN + col0 + cb] = f;
        }
        cnti += __shfl_down(cnti, 1);
        cnti += __shfl_down(cnti, 2);
        if (q == 0 && cnti) atomicAdd(&deg[row0 + r], cnti);
    }

    // ---- mirror region (bx,by) for off-diagonal blocks ----
    if (!diag) {
        int c = tid >> 2, q = tid & 3;
        int cnti = 0;
        float4 fz = {0.0f, 0.0f, 0.0f, 0.0f};   // col0+c > row0+r always -> lm=0
#pragma unroll
        for (int s = 0; s < 4; ++s) {
            int rb = q * 16 + s * 4;
            us4 a4;
#pragma unroll
            for (int k2 = 0; k2 < 4; ++k2) {
                bool fl = flags[(rb + k2) * 68 + c] != 0;
                cnti += fl ? 1 : 0;
                ((ushortT*)&a4)[k2] = fl ? (ushortT)0x3F80 : (ushortT)0;
            }
            *(us4*)&ab[(size_t)(col0 + c) * NN + row0 + rb] = a4;
            *(float4*)&lm[(size_t)(col0 + c) * NN + row0 + rb] = fz;
        }
        cnti += __shfl_down(cnti, 1);
        cnti += __shfl_down(cnti, 2);
        if (q == 0 && cnti) atomicAdd(&deg[col0 + c], cnti);
    }
}

__global__ void dinv_kernel(const int* __restrict__ deg, float* __restrict__ dinv) {
    int i = blockIdx.x * blockDim.x + threadIdx.x;
    if (i < NN) dinv[i] = (float)(1.0 / sqrt((double)(1 + deg[i])));
}

// ---------------------------------------------------------------------------
// PREP (fused): b<4096: row b -> f_g x-cols, x-out, xb bf16.
// b in [4096,4480): W1 transpose-to-bf16 tile. b in [4480,4512): W2 ditto.
// ---------------------------------------------------------------------------
__global__ __launch_bounds__(256) void prep_kernel(
    const float* __restrict__ x, const float* __restrict__ W1,
    const float* __restrict__ W2, float* __restrict__ fg, float* __restrict__ xo,
    ushortT* __restrict__ xb, ushortT* __restrict__ w1t, ushortT* __restrict__ w2t) {
    int b = blockIdx.x;
    if (b < 4096) {
        int t = threadIdx.x;
        if (t < 192) {
            float4 v = *(const float4*)&x[(size_t)b * CD + t * 4];
            *(float4*)&xo[(size_t)b * CD + t * 4] = v;
            fg[(size_t)b * FGD + t * 4 + 0] = v.x;
            fg[(size_t)b * FGD + t * 4 + 1] = v.y;
            fg[(size_t)b * FGD + t * 4 + 2] = v.z;
            fg[(size_t)b * FGD + t * 4 + 3] = v.w;
            us4 bb;
            ((ushortT*)&bb)[0] = f2bf(v.x);
            ((ushortT*)&bb)[1] = f2bf(v.y);
            ((ushortT*)&bb)[2] = f2bf(v.z);
            ((ushortT*)&bb)[3] = f2bf(v.w);
            *(us4*)&xb[(size_t)b * CD + t * 4] = bb;
        }
        return;
    }
    // transpose branches
    __shared__ float tT[32][33];
    const float* P;
    ushortT* T;
    int K, N, Npad, k0, n0;
    if (b < 4480) {
        int bb = b - 4096;                  // 24 x 16 tiles
        P = W1; T = w1t; K = CD; N = HD; Npad = HD;
        k0 = (bb % 24) * 32; n0 = (bb / 24) * 32;
    } else {
        int bb = b - 4480;                  // 16 x 2 tiles
        P = W2; T = w2t; K = HD; N = OD; Npad = 64;
        k0 = (bb % 16) * 32; n0 = (bb / 16) * 32;
    }
    int tx = threadIdx.x & 31, ty = threadIdx.x >> 5;
#pragma unroll
    for (int s = 0; s < 4; ++s) {
        int k = k0 + ty + s * 8, n = n0 + tx;
        tT[ty + s * 8][tx] = (k < K && n < N) ? P[(size_t)k * N + n] : 0.0f;
    }
    __syncthreads();
#pragma unroll
    for (int s = 0; s < 4; ++s) {
        int n = n0 + ty + s * 8, k = k0 + tx;
        if (n < Npad && k < K) T[(size_t)n * K + k] = f2bf(tT[tx][ty + s * 8]);
    }
}

// ---------------------------------------------------------------------------
// bf16-MFMA GEMM (verified R6). A row-major MxK; B transposed [Npad][K].
// EPI: 0 = fp32 out, 1 = bf16 row-major, 2 = bf16 transposed out.
// ---------------------------------------------------------------------------
template <bool RELU, bool HASBIAS, int EPI>
__global__ __launch_bounds__(256) void gemm_bf16(
    const ushortT* __restrict__ A, const ushortT* __restrict__ B,
    float* __restrict__ C, ushortT* __restrict__ Cb,
    int M, int Nn, int K, int ldc,
    const float* __restrict__ rowscale, const float* __restrict__ bias) {
    __shared__ ushortT lds[2 * 64 * 72];    // 18432 B
    int tid = threadIdx.x;
    int lane = tid & 63;
    int w = tid >> 6;
    int wr = w >> 1, wc = w & 1;
    int m = lane & 15, quad = lane >> 4;
    int row0 = blockIdx.y * 64, col0 = blockIdx.x * 64;

    f32x4 acc[2][2] = {{{0.f, 0.f, 0.f, 0.f}, {0.f, 0.f, 0.f, 0.f}},
                       {{0.f, 0.f, 0.f, 0.f}, {0.f, 0.f, 0.f, 0.f}}};

    for (int k0 = 0; k0 < K; k0 += 64) {
#pragma unroll
        for (int t = 0; t < 2; ++t) {
            int id2 = tid + t * 256;
            int row = id2 >> 3, c8 = (id2 & 7) * 8;
            *(short8*)&lds[row * 72 + c8] =
                *(const short8*)&A[(size_t)(row0 + row) * K + k0 + c8];
            *(short8*)&lds[4608 + row * 72 + c8] =
                *(const short8*)&B[(size_t)(col0 + row) * K + k0 + c8];
        }
        __syncthreads();
#pragma unroll
        for (int ks = 0; ks < 2; ++ks) {
            short8 af[2], bf[2];
#pragma unroll
            for (int i = 0; i < 2; ++i)
                af[i] = *(const short8*)&lds[(wr * 32 + i * 16 + m) * 72 +
                                             ks * 32 + quad * 8];
#pragma unroll
            for (int j = 0; j < 2; ++j)
                bf[j] = *(const short8*)&lds[4608 + (wc * 32 + j * 16 + m) * 72 +
                                             ks * 32 + quad * 8];
#pragma unroll
            for (int i = 0; i < 2; ++i)
#pragma unroll
                for (int j = 0; j < 2; ++j)
                    acc[i][j] = __builtin_amdgcn_mfma_f32_16x16x32_bf16(
                        af[i], bf[j], acc[i][j], 0, 0, 0);
        }
        __syncthreads();
    }

    if (EPI == 2) {
        ushortT* Th = lds;
#pragma unroll
        for (int i = 0; i < 2; ++i)
#pragma unroll
            for (int j = 0; j < 2; ++j)
#pragma unroll
                for (int r = 0; r < 4; ++r) {
                    int row = wr * 32 + i * 16 + quad * 4 + r;
                    int col = wc * 32 + j * 16 + m;
                    Th[col * 72 + row] = f2bf(acc[i][j][r] * rowscale[row0 + row]);
                }
        __syncthreads();
#pragma unroll
        for (int t = 0; t < 2; ++t) {
            int id2 = tid + t * 256;
            int cc = id2 >> 3, chunk = id2 & 7;
            *(short8*)&Cb[(size_t)(col0 + cc) * M + row0 + chunk * 8] =
                *(const short8*)&Th[cc * 72 + chunk * 8];
        }
    } else {
#pragma unroll
        for (int i = 0; i < 2; ++i)
#pragma unroll
            for (int j = 0; j < 2; ++j)
#pragma unroll
                for (int r = 0; r < 4; ++r) {
                    int row = wr * 32 + i * 16 + quad * 4 + r;
                    int col = wc * 32 + j * 16 + m;
                    int gr = row0 + row, gc = col0 + col;
                    if (gc < Nn) {
                        float v = acc[i][j][r] * rowscale[gr];
                        if (HASBIAS) v += bias[gc];
                        if (RELU) v = fmaxf(v, 0.0f);
                        if (EPI == 0) C[(size_t)gr * ldc + gc] = v;
                        else Cb[(size_t)gr * ldc + gc] = f2bf(v);
                    }
                }
    }
}

// ---------------------------------------------------------------------------
// out[i] = f_g[i,:] . fcW + fcb
// ---------------------------------------------------------------------------
__global__ __launch_bounds__(256) void out_kernel(const float* __restrict__ fg,
                                                  const float* __restrict__ fcW,
                                                  const float* __restrict__ fcb,
                                                  float* __restrict__ out) {
    int i = blockIdx.x;
    float s = 0.0f;
    for (int j = threadIdx.x; j < FGD; j += 256)
        s += fg[(size_t)i * FGD + j] * fcW[j];
    for (int off = 32; off; off >>= 1) s += __shfl_down(s, off);
    __shared__ float sw[4];
    int wid = threadIdx.x >> 6, lane = threadIdx.x & 63;
    if (lane == 0) sw[wid] = s;
    __syncthreads();
    if (threadIdx.x == 0) out[i] = sw[0] + sw[1] + sw[2] + sw[3] + fcb[0];
}

extern "C" void kernel_launch(void* const* d_in, const int* in_sizes, int n_in,
                              void* d_out, int out_size, void* d_ws, size_t ws_size,
                              hipStream_t stream) {
    const float* x = (const float*)d_in[0];
    const int* labels = (const int*)d_in[1];
    const float* W1 = (const float*)d_in[2];
    const float* b1 = (const float*)d_in[3];
    const float* W2 = (const float*)d_in[4];
    const float* b2 = (const float*)d_in[5];
    const float* fcW = (const float*)d_in[6];
    const float* fcb = (const float*)d_in[7];
    float* outp = (float*)d_out;

    const size_t o_out = 0;
    const size_t o_fg = 4096;
    const size_t o_lm = o_fg + (size_t)NN * FGD;
    const size_t o_x = o_lm + (size_t)NN * NN;

    // workspace layout
    char* ws = (char*)d_ws;
    size_t off = 0;
    ushortT* ab = (ushortT*)(ws + off); off += (size_t)NN * NN * 2;     // 32 MiB
    ushortT* xb = (ushortT*)(ws + off); off += (size_t)NN * CD * 2;
    ushortT* w1t = (ushortT*)(ws + off); off += (size_t)HD * CD * 2;
    ushortT* xw1sT = (ushortT*)(ws + off); off += (size_t)HD * NN * 2;
    ushortT* hb = (ushortT*)(ws + off); off += (size_t)NN * HD * 2;
    ushortT* w2t = (ushortT*)(ws + off); off += (size_t)64 * HD * 2;
    ushortT* hw2sT = (ushortT*)(ws + off); off += (size_t)64 * NN * 2;
    float* dinv = (float*)(ws + off); off += (size_t)NN * 4;
    // zero-init region (one memset): deg | gsum | scal
    char* zbase = ws + off;
    int* deg = (int*)(ws + off); off += (size_t)NN * 4;
    double* gsum = (double*)(ws + off); off += 1536 * 8;
    double* scal = (double*)(ws + off); off += 16;
    size_t zbytes = (size_t)NN * 4 + 1536 * 8 + 16;

    hipMemsetAsync(zbase, 0, zbytes, stream);

    // threshold via group sums (no sim matrix needed)
    gsum_kernel<<<256, 256, 0, stream>>>(x, labels, gsum);
    gdot_kernel<<<1, 256, 0, stream>>>(gsum, labels, scal);

    // fused sim + mask + adjacency + degrees (triangular grid, 2080 blocks)
    sim_fused<<<2080, 256, 0, stream>>>(x, labels, scal, ab, outp + o_lm, deg);

    // prep: x copies/casts + weight transposes (one kernel)
    prep_kernel<<<4512, 256, 0, stream>>>(x, W1, W2, outp + o_fg, outp + o_x, xb,
                                          w1t, w2t);

    dinv_kernel<<<(NN + 255) / 256, 256, 0, stream>>>(deg, dinv);

    // K4: xw1sT = (dinv ⊙ (x @ W1))^T   [M=4096,N=512,K=768]
    gemm_bf16<false, false, 2><<<dim3(HD / 64, NN / 64), 256, 0, stream>>>(
        xb, w1t, nullptr, xw1sT, NN, HD, CD, 0, dinv, nullptr);

    // K5: h = relu(dinv ⊙ (a @ xw1s) + b1), bf16 row-major  [K=4096]
    gemm_bf16<true, true, 1><<<dim3(HD / 64, NN / 64), 256, 0, stream>>>(
        ab, xw1sT, nullptr, hb, NN, HD, NN, HD, dinv, b1);

    // K6: hw2sT = (dinv ⊙ (h @ W2))^T   [N=50->64, K=512]
    gemm_bf16<false, false, 2><<<dim3(1, NN / 64), 256, 0, stream>>>(
        hb, w2t, nullptr, hw2sT, NN, OD, HD, 0, dinv, nullptr);

    // K7: g = dinv ⊙ (a @ hw2s) + b2 -> f_g[:, 768:818] fp32  [K=4096]
    gemm_bf16<false, true, 0><<<dim3(1, NN / 64), 256, 0, stream>>>(
        ab, hw2sT, outp + o_fg + CD, nullptr, NN, OD, NN, FGD, dinv, b2);

    out_kernel<<<NN, 256, 0, stream>>>(outp + o_fg, fcW, fcb, outp + o_out);
}

// Round 8
// 494.449 us; speedup vs baseline: 1.4646x; 1.3131x over previous
//
#include <hip/hip_runtime.h>
#include <hip/hip_bf16.h>
#include <math.h>

#define NN 4096
#define CD 768
#define HD 512
#define OD 50
#define FGD 818   // CD + OD

typedef short short8 __attribute__((ext_vector_type(8)));
typedef float f32x4 __attribute__((ext_vector_type(4)));
typedef unsigned short us4 __attribute__((ext_vector_type(4)));
typedef unsigned short ushortT;
typedef unsigned char uchar;

__device__ inline ushortT f2bf(float v) {
    __hip_bfloat16 b = __float2bfloat16(v);
    return *(ushortT*)&b;
}
__device__ inline float bf2f(ushortT u) {
    __hip_bfloat16 b = *(__hip_bfloat16*)&u;
    return __bfloat162float(b);
}

// ---------------------------------------------------------------------------
// K0a: per-label group sums of x columns (fp64).  gsum[0..767]=L0, [768..]=L1
// ---------------------------------------------------------------------------
__global__ __launch_bounds__(256) void gsum_kernel(const float* __restrict__ x,
                                                   const int* __restrict__ labels,
                                                   double* __restrict__ gsum) {
    int b = blockIdx.x;
    int t = threadIdx.x;
    double a0[3] = {0, 0, 0}, a1[3] = {0, 0, 0};
    for (int rr = 0; rr < 16; ++rr) {
        int row = b * 16 + rr;
        int lab = labels[row];
#pragma unroll
        for (int s = 0; s < 3; ++s) {
            double v = (double)x[(size_t)row * CD + t + s * 256];
            if (lab == 0) a0[s] += v; else a1[s] += v;
        }
    }
#pragma unroll
    for (int s = 0; s < 3; ++s) {
        atomicAdd(&gsum[t + s * 256], a0[s]);
        atomicAdd(&gsum[768 + t + s * 256], a1[s]);
    }
}

// ---------------------------------------------------------------------------
// K0b: threshold scalars. scal[0] = 2*S0.S1, scal[1] = 2*n0*n1.
// ---------------------------------------------------------------------------
__global__ __launch_bounds__(256) void gdot_kernel(const double* __restrict__ gsum,
                                                   const int* __restrict__ labels,
                                                   double* __restrict__ scal) {
    int t = threadIdx.x;
    double d = 0.0;
    for (int c = t; c < CD; c += 256) d += gsum[c] * gsum[768 + c];
    int n0 = 0;
    for (int i = t; i < NN; i += 256) n0 += (labels[i] == 0) ? 1 : 0;
    for (int off = 32; off; off >>= 1) {
        d += __shfl_down(d, off);
        n0 += __shfl_down(n0, off);
    }
    __shared__ double sd[4];
    __shared__ int sn[4];
    int wid = t >> 6, lane = t & 63;
    if (lane == 0) { sd[wid] = d; sn[wid] = n0; }
    __syncthreads();
    if (t == 0) {
        double D = sd[0] + sd[1] + sd[2] + sd[3];
        double N0 = (double)(sn[0] + sn[1] + sn[2] + sn[3]);
        scal[0] = 2.0 * D;
        scal[1] = 2.0 * N0 * ((double)NN - N0);
    }
}

// ---------------------------------------------------------------------------
// K1: FUSED sim+mask via bf16 3-term split MFMA (hi*hi + hi*lo + lo*hi,
// fp32 acc; verified m89 fragment layout). Entries within +-BAND of thr are
// re-verified with an exact inline fp64 dot -> decisions match the fp64 path
// (validated R3..R7). Emits ab (bf16 0/1), lm (fp32 0/1), deg atomics.
// Triangular 2080-block grid; 64x64 tiles; 4 waves -> 32x32 each.
// ---------------------------------------------------------------------------
#define BAND 4e-3

__global__ __launch_bounds__(256) void sim_fused(
    const float* __restrict__ x, const ushortT* __restrict__ xh,
    const ushortT* __restrict__ xl, const int* __restrict__ labels,
    const double* __restrict__ scal, ushortT* __restrict__ ab,
    float* __restrict__ lm, int* __restrict__ deg) {
    // triangular mapping: t -> (by, bx), bx >= by
    int t = blockIdx.x;
    int by = (int)((129.0 - sqrt(16641.0 - 8.0 * (double)t)) * 0.5);
    while (by * (129 - by) / 2 > t) --by;
    while ((by + 1) * (129 - (by + 1)) / 2 <= t) ++by;
    int bx = by + (t - by * (129 - by) / 2);
    bool diag = (bx == by);

    __shared__ ushortT lds[4 * 64 * 72];    // 36864 B: Rh|Rl|Ch|Cl, then flags
    __shared__ int larr[128];
    int tid = threadIdx.x;
    int lane = tid & 63;
    int w = tid >> 6;
    int wr = w >> 1, wc = w & 1;
    int m = lane & 15, quad = lane >> 4;
    int row0 = by * 64, col0 = bx * 64;

    if (tid < 64) larr[tid] = labels[row0 + tid];
    else if (tid < 128) larr[tid] = labels[col0 + tid - 64];

    f32x4 acc[2][2] = {{{0.f, 0.f, 0.f, 0.f}, {0.f, 0.f, 0.f, 0.f}},
                       {{0.f, 0.f, 0.f, 0.f}, {0.f, 0.f, 0.f, 0.f}}};

    for (int k0 = 0; k0 < CD; k0 += 64) {
#pragma unroll
        for (int tt = 0; tt < 2; ++tt) {
            int id2 = tid + tt * 256;
            int row = id2 >> 3, c8 = (id2 & 7) * 8;
            *(short8*)&lds[0 * 4608 + row * 72 + c8] =
                *(const short8*)&xh[(size_t)(row0 + row) * CD + k0 + c8];
            *(short8*)&lds[1 * 4608 + row * 72 + c8] =
                *(const short8*)&xl[(size_t)(row0 + row) * CD + k0 + c8];
            *(short8*)&lds[2 * 4608 + row * 72 + c8] =
                *(const short8*)&xh[(size_t)(col0 + row) * CD + k0 + c8];
            *(short8*)&lds[3 * 4608 + row * 72 + c8] =
                *(const short8*)&xl[(size_t)(col0 + row) * CD + k0 + c8];
        }
        __syncthreads();
#pragma unroll
        for (int ks = 0; ks < 2; ++ks) {
            short8 ah[2], al[2], bh[2], bl[2];
#pragma unroll
            for (int i = 0; i < 2; ++i) {
                int ro = (wr * 32 + i * 16 + m) * 72 + ks * 32 + quad * 8;
                ah[i] = *(const short8*)&lds[0 * 4608 + ro];
                al[i] = *(const short8*)&lds[1 * 4608 + ro];
            }
#pragma unroll
            for (int j = 0; j < 2; ++j) {
                int co = (wc * 32 + j * 16 + m) * 72 + ks * 32 + quad * 8;
                bh[j] = *(const short8*)&lds[2 * 4608 + co];
                bl[j] = *(const short8*)&lds[3 * 4608 + co];
            }
#pragma unroll
            for (int i = 0; i < 2; ++i)
#pragma unroll
                for (int j = 0; j < 2; ++j) {
                    acc[i][j] = __builtin_amdgcn_mfma_f32_16x16x32_bf16(
                        ah[i], bh[j], acc[i][j], 0, 0, 0);
                    acc[i][j] = __builtin_amdgcn_mfma_f32_16x16x32_bf16(
                        ah[i], bl[j], acc[i][j], 0, 0, 0);
                    acc[i][j] = __builtin_amdgcn_mfma_f32_16x16x32_bf16(
                        al[i], bh[j], acc[i][j], 0, 0, 0);
                }
        }
        __syncthreads();
    }

    // ---- edge flags (alias staging LDS; all reads of tiles are done) ----
    double thrd;
    {
        double cnt = scal[1];
        thrd = (cnt > 0.0) ? (scal[0] / cnt) : 0.0;
    }
    uchar* flags = (uchar*)lds;             // [64][68]
#pragma unroll
    for (int i = 0; i < 2; ++i)
#pragma unroll
        for (int j = 0; j < 2; ++j) {
#pragma unroll
            for (int r = 0; r < 4; ++r) {
                int row = wr * 32 + i * 16 + quad * 4 + r;
                int col = wc * 32 + j * 16 + m;
                bool same = (larr[row] == larr[64 + col]);
                bool selfp = ((row0 + row) == (col0 + col));
                bool edge = false;
                if (same && !selfp) {
                    double s = (double)acc[i][j][r];
                    if (s <= thrd - BAND) {
                        edge = true;
                    } else if (s <= thrd + BAND) {
                        // ambiguous: exact fp64 dot (rare; L2-hot x)
                        const float* xi = x + (size_t)(row0 + row) * CD;
                        const float* xj = x + (size_t)(col0 + col) * CD;
                        double e0 = 0.0, e1 = 0.0;
                        for (int k = 0; k < CD; k += 2) {
                            e0 += (double)xi[k] * (double)xj[k];
                            e1 += (double)xi[k + 1] * (double)xj[k + 1];
                        }
                        edge = ((e0 + e1) <= thrd);
                    }
                }
                flags[row * 68 + col] = edge ? 1 : 0;
            }
        }
    __syncthreads();

    // ---- write ab/lm rows for (by,bx) region + row degrees ----
    {
        int r = tid >> 2, q = tid & 3;
        int cnti = 0;
#pragma unroll
        for (int s = 0; s < 4; ++s) {
            int cb = q * 16 + s * 4;
            float4 f;
            us4 a4;
#pragma unroll
            for (int k2 = 0; k2 < 4; ++k2) {
                int c = cb + k2;
                bool fl = flags[r * 68 + c] != 0;
                cnti += fl ? 1 : 0;
                ((ushortT*)&a4)[k2] =
                    (fl || (diag && r == c)) ? (ushortT)0x3F80 : (ushortT)0;
                ((float*)&f)[k2] = (fl && (row0 + r < col0 + c)) ? 1.0f : 0.0f;
            }
            *(us4*)&ab[(size_t)(row0 + r) * NN + col0 + cb] = a4;
            *(float4*)&lm[(size_t)(row0 + r) * NN + col0 + cb] = f;
        }
        cnti += __shfl_down(cnti, 1);
        cnti += __shfl_down(cnti, 2);
        if (q == 0 && cnti) atomicAdd(&deg[row0 + r], cnti);
    }

    // ---- mirror region (bx,by) for off-diagonal blocks ----
    if (!diag) {
        int c = tid >> 2, q = tid & 3;
        int cnti = 0;
        float4 fz = {0.0f, 0.0f, 0.0f, 0.0f};
#pragma unroll
        for (int s = 0; s < 4; ++s) {
            int rb = q * 16 + s * 4;
            us4 a4;
#pragma unroll
            for (int k2 = 0; k2 < 4; ++k2) {
                bool fl = flags[(rb + k2) * 68 + c] != 0;
                cnti += fl ? 1 : 0;
                ((ushortT*)&a4)[k2] = fl ? (ushortT)0x3F80 : (ushortT)0;
            }
            *(us4*)&ab[(size_t)(col0 + c) * NN + row0 + rb] = a4;
            *(float4*)&lm[(size_t)(col0 + c) * NN + row0 + rb] = fz;
        }
        cnti += __shfl_down(cnti, 1);
        cnti += __shfl_down(cnti, 2);
        if (q == 0 && cnti) atomicAdd(&deg[col0 + c], cnti);
    }
}

__global__ void dinv_kernel(const int* __restrict__ deg, float* __restrict__ dinv) {
    int i = blockIdx.x * blockDim.x + threadIdx.x;
    if (i < NN) dinv[i] = (float)(1.0 / sqrt((double)(1 + deg[i])));
}

// ---------------------------------------------------------------------------
// PREP (fused): b<4096: row b -> f_g x-cols, x-out, xh/xl bf16 planes.
// b in [4096,4480): W1 transpose tile. b in [4480,4512): W2 ditto.
// ---------------------------------------------------------------------------
__global__ __launch_bounds__(256) void prep_kernel(
    const float* __restrict__ x, const float* __restrict__ W1,
    const float* __restrict__ W2, float* __restrict__ fg, float* __restrict__ xo,
    ushortT* __restrict__ xh, ushortT* __restrict__ xl, ushortT* __restrict__ w1t,
    ushortT* __restrict__ w2t) {
    int b = blockIdx.x;
    if (b < 4096) {
        int t = threadIdx.x;
        if (t < 192) {
            float4 v = *(const float4*)&x[(size_t)b * CD + t * 4];
            *(float4*)&xo[(size_t)b * CD + t * 4] = v;
            fg[(size_t)b * FGD + t * 4 + 0] = v.x;
            fg[(size_t)b * FGD + t * 4 + 1] = v.y;
            fg[(size_t)b * FGD + t * 4 + 2] = v.z;
            fg[(size_t)b * FGD + t * 4 + 3] = v.w;
            us4 hh, ll;
            float* vp = (float*)&v;
#pragma unroll
            for (int k = 0; k < 4; ++k) {
                ushortT h = f2bf(vp[k]);
                ((ushortT*)&hh)[k] = h;
                ((ushortT*)&ll)[k] = f2bf(vp[k] - bf2f(h));
            }
            *(us4*)&xh[(size_t)b * CD + t * 4] = hh;
            *(us4*)&xl[(size_t)b * CD + t * 4] = ll;
        }
        return;
    }
    __shared__ float tT[32][33];
    const float* P;
    ushortT* T;
    int K, N, Npad, k0, n0;
    if (b < 4480) {
        int bb = b - 4096;
        P = W1; T = w1t; K = CD; N = HD; Npad = HD;
        k0 = (bb % 24) * 32; n0 = (bb / 24) * 32;
    } else {
        int bb = b - 4480;
        P = W2; T = w2t; K = HD; N = OD; Npad = 64;
        k0 = (bb % 16) * 32; n0 = (bb / 16) * 32;
    }
    int tx = threadIdx.x & 31, ty = threadIdx.x >> 5;
#pragma unroll
    for (int s = 0; s < 4; ++s) {
        int k = k0 + ty + s * 8, n = n0 + tx;
        tT[ty + s * 8][tx] = (k < K && n < N) ? P[(size_t)k * N + n] : 0.0f;
    }
    __syncthreads();
#pragma unroll
    for (int s = 0; s < 4; ++s) {
        int n = n0 + ty + s * 8, k = k0 + tx;
        if (n < Npad && k < K) T[(size_t)n * K + k] = f2bf(tT[tx][ty + s * 8]);
    }
}

// ---------------------------------------------------------------------------
// bf16-MFMA GEMM (verified R6/R7). A row-major MxK; B transposed [Npad][K].
// EPI: 0 = fp32 out, 1 = bf16 row-major, 2 = bf16 transposed out.
// ---------------------------------------------------------------------------
template <bool RELU, bool HASBIAS, int EPI>
__global__ __launch_bounds__(256) void gemm_bf16(
    const ushortT* __restrict__ A, const ushortT* __restrict__ B,
    float* __restrict__ C, ushortT* __restrict__ Cb,
    int M, int Nn, int K, int ldc,
    const float* __restrict__ rowscale, const float* __restrict__ bias) {
    __shared__ ushortT lds[2 * 64 * 72];
    int tid = threadIdx.x;
    int lane = tid & 63;
    int w = tid >> 6;
    int wr = w >> 1, wc = w & 1;
    int m = lane & 15, quad = lane >> 4;
    int row0 = blockIdx.y * 64, col0 = blockIdx.x * 64;

    f32x4 acc[2][2] = {{{0.f, 0.f, 0.f, 0.f}, {0.f, 0.f, 0.f, 0.f}},
                       {{0.f, 0.f, 0.f, 0.f}, {0.f, 0.f, 0.f, 0.f}}};

    for (int k0 = 0; k0 < K; k0 += 64) {
#pragma unroll
        for (int t = 0; t < 2; ++t) {
            int id2 = tid + t * 256;
            int row = id2 >> 3, c8 = (id2 & 7) * 8;
            *(short8*)&lds[row * 72 + c8] =
                *(const short8*)&A[(size_t)(row0 + row) * K + k0 + c8];
            *(short8*)&lds[4608 + row * 72 + c8] =
                *(const short8*)&B[(size_t)(col0 + row) * K + k0 + c8];
        }
        __syncthreads();
#pragma unroll
        for (int ks = 0; ks < 2; ++ks) {
            short8 af[2], bf[2];
#pragma unroll
            for (int i = 0; i < 2; ++i)
                af[i] = *(const short8*)&lds[(wr * 32 + i * 16 + m) * 72 +
                                             ks * 32 + quad * 8];
#pragma unroll
            for (int j = 0; j < 2; ++j)
                bf[j] = *(const short8*)&lds[4608 + (wc * 32 + j * 16 + m) * 72 +
                                             ks * 32 + quad * 8];
#pragma unroll
            for (int i = 0; i < 2; ++i)
#pragma unroll
                for (int j = 0; j < 2; ++j)
                    acc[i][j] = __builtin_amdgcn_mfma_f32_16x16x32_bf16(
                        af[i], bf[j], acc[i][j], 0, 0, 0);
        }
        __syncthreads();
    }

    if (EPI == 2) {
        ushortT* Th = lds;
#pragma unroll
        for (int i = 0; i < 2; ++i)
#pragma unroll
            for (int j = 0; j < 2; ++j)
#pragma unroll
                for (int r = 0; r < 4; ++r) {
                    int row = wr * 32 + i * 16 + quad * 4 + r;
                    int col = wc * 32 + j * 16 + m;
                    Th[col * 72 + row] = f2bf(acc[i][j][r] * rowscale[row0 + row]);
                }
        __syncthreads();
#pragma unroll
        for (int t = 0; t < 2; ++t) {
            int id2 = tid + t * 256;
            int cc = id2 >> 3, chunk = id2 & 7;
            *(short8*)&Cb[(size_t)(col0 + cc) * M + row0 + chunk * 8] =
                *(const short8*)&Th[cc * 72 + chunk * 8];
        }
    } else {
#pragma unroll
        for (int i = 0; i < 2; ++i)
#pragma unroll
            for (int j = 0; j < 2; ++j)
#pragma unroll
                for (int r = 0; r < 4; ++r) {
                    int row = wr * 32 + i * 16 + quad * 4 + r;
                    int col = wc * 32 + j * 16 + m;
                    int gr = row0 + row, gc = col0 + col;
                    if (gc < Nn) {
                        float v = acc[i][j][r] * rowscale[gr];
                        if (HASBIAS) v += bias[gc];
                        if (RELU) v = fmaxf(v, 0.0f);
                        if (EPI == 0) C[(size_t)gr * ldc + gc] = v;
                        else Cb[(size_t)gr * ldc + gc] = f2bf(v);
                    }
                }
    }
}

// ---------------------------------------------------------------------------
// out[i] = f_g[i,:] . fcW + fcb
// ---------------------------------------------------------------------------
__global__ __launch_bounds__(256) void out_kernel(const float* __restrict__ fg,
                                                  const float* __restrict__ fcW,
                                                  const float* __restrict__ fcb,
                                                  float* __restrict__ out) {
    int i = blockIdx.x;
    float s = 0.0f;
    for (int j = threadIdx.x; j < FGD; j += 256)
        s += fg[(size_t)i * FGD + j] * fcW[j];
    for (int off = 32; off; off >>= 1) s += __shfl_down(s, off);
    __shared__ float sw[4];
    int wid = threadIdx.x >> 6, lane = threadIdx.x & 63;
    if (lane == 0) sw[wid] = s;
    __syncthreads();
    if (threadIdx.x == 0) out[i] = sw[0] + sw[1] + sw[2] + sw[3] + fcb[0];
}

extern "C" void kernel_launch(void* const* d_in, const int* in_sizes, int n_in,
                              void* d_out, int out_size, void* d_ws, size_t ws_size,
                              hipStream_t stream) {
    const float* x = (const float*)d_in[0];
    const int* labels = (const int*)d_in[1];
    const float* W1 = (const float*)d_in[2];
    const float* b1 = (const float*)d_in[3];
    const float* W2 = (const float*)d_in[4];
    const float* b2 = (const float*)d_in[5];
    const float* fcW = (const float*)d_in[6];
    const float* fcb = (const float*)d_in[7];
    float* outp = (float*)d_out;

    const size_t o_out = 0;
    const size_t o_fg = 4096;
    const size_t o_lm = o_fg + (size_t)NN * FGD;
    const size_t o_x = o_lm + (size_t)NN * NN;

    // workspace layout
    char* ws = (char*)d_ws;
    size_t off = 0;
    ushortT* ab = (ushortT*)(ws + off); off += (size_t)NN * NN * 2;     // 32 MiB
    ushortT* xh = (ushortT*)(ws + off); off += (size_t)NN * CD * 2;
    ushortT* xl = (ushortT*)(ws + off); off += (size_t)NN * CD * 2;
    ushortT* w1t = (ushortT*)(ws + off); off += (size_t)HD * CD * 2;
    ushortT* xw1sT = (ushortT*)(ws + off); off += (size_t)HD * NN * 2;
    ushortT* hb = (ushortT*)(ws + off); off += (size_t)NN * HD * 2;
    ushortT* w2t = (ushortT*)(ws + off); off += (size_t)64 * HD * 2;
    ushortT* hw2sT = (ushortT*)(ws + off); off += (size_t)64 * NN * 2;
    float* dinv = (float*)(ws + off); off += (size_t)NN * 4;
    char* zbase = ws + off;
    int* deg = (int*)(ws + off); off += (size_t)NN * 4;
    double* gsum = (double*)(ws + off); off += 1536 * 8;
    double* scal = (double*)(ws + off); off += 16;
    size_t zbytes = (size_t)NN * 4 + 1536 * 8 + 16;

    hipMemsetAsync(zbase, 0, zbytes, stream);

    // prep: x copies/casts (hi+lo planes) + weight transposes
    prep_kernel<<<4512, 256, 0, stream>>>(x, W1, W2, outp + o_fg, outp + o_x, xh, xl,
                                          w1t, w2t);

    // threshold via group sums (exact fp64, no sim matrix)
    gsum_kernel<<<256, 256, 0, stream>>>(x, labels, gsum);
    gdot_kernel<<<1, 256, 0, stream>>>(gsum, labels, scal);

    // fused sim(bf16-split + fp64 recheck) + mask + adjacency + degrees
    sim_fused<<<2080, 256, 0, stream>>>(x, xh, xl, labels, scal, ab, outp + o_lm, deg);

    dinv_kernel<<<(NN + 255) / 256, 256, 0, stream>>>(deg, dinv);

    // K4: xw1sT = (dinv ⊙ (x @ W1))^T   [M=4096,N=512,K=768]
    gemm_bf16<false, false, 2><<<dim3(HD / 64, NN / 64), 256, 0, stream>>>(
        xh, w1t, nullptr, xw1sT, NN, HD, CD, 0, dinv, nullptr);

    // K5: h = relu(dinv ⊙ (a @ xw1s) + b1), bf16 row-major  [K=4096]
    gemm_bf16<true, true, 1><<<dim3(HD / 64, NN / 64), 256, 0, stream>>>(
        ab, xw1sT, nullptr, hb, NN, HD, NN, HD, dinv, b1);

    // K6: hw2sT = (dinv ⊙ (h @ W2))^T   [N=50->64, K=512]
    gemm_bf16<false, false, 2><<<dim3(1, NN / 64), 256, 0, stream>>>(
        hb, w2t, nullptr, hw2sT, NN, OD, HD, 0, dinv, nullptr);

    // K7: g = dinv ⊙ (a @ hw2s) + b2 -> f_g[:, 768:818] fp32  [K=4096]
    gemm_bf16<false, true, 0><<<dim3(1, NN / 64), 256, 0, stream>>>(
        ab, hw2sT, outp + o_fg + CD, nullptr, NN, OD, NN, FGD, dinv, b2);

    out_kernel<<<NN, 256, 0, stream>>>(outp + o_fg, fcW, fcb, outp + o_out);
}